// Round 1
// baseline (736.753 us; speedup 1.0000x reference)
//
#include <hip/hip_runtime.h>

#define IC 4096
#define NWAVES 8
#define IPW 4        // i-values register-cached per wave
#define BHALF 128    // batch elements per block

// One routing pass: for each (b,i) recompute u[a,d] = sum_c x[b,i,c]*W[a,i,d,c],
// weight by c[a] (uniform 1/16 if USEV==0, else softmax over a of IC*(u . vprev)),
// and atomically accumulate s[b,a,d] += c[a]*u[a,d].
template<int USEV>
__global__ __launch_bounds__(512, 2)
void caps_pass(const float* __restrict__ x, const float* __restrict__ W,
               const float* __restrict__ vprev, float* __restrict__ s_out)
{
    __shared__ float lds[NWAVES][256];
    const int tid  = threadIdx.x;
    const int wu   = __builtin_amdgcn_readfirstlane(tid >> 6);  // wave id 0..7 (uniform)
    const int lane = tid & 63;
    const int a    = lane >> 2;   // capsule 0..15
    const int dq   = lane & 3;    // d-quad: this lane owns d = dq*4 .. dq*4+3
    const int ichunk = (int)blockIdx.x >> 1;
    const int bhalf  = (int)blockIdx.x & 1;
    const int i0 = ichunk * (NWAVES * IPW) + wu * IPW;

    // Register-cache W[a, i0..i0+3, dq*4..dq*4+3, 0..7]: 32 contiguous floats per i.
    float w[IPW][32];
#pragma unroll
    for (int ii = 0; ii < IPW; ++ii) {
        const float* wp = W + ((size_t)a * IC + (size_t)(i0 + ii)) * 128 + dq * 32;
#pragma unroll
        for (int q = 0; q < 8; ++q) {
            const float4 f = *(const float4*)(wp + q * 4);
            w[ii][q * 4 + 0] = f.x; w[ii][q * 4 + 1] = f.y;
            w[ii][q * 4 + 2] = f.z; w[ii][q * 4 + 3] = f.w;
        }
    }

    for (int bb = 0; bb < BHALF; ++bb) {
        const int b = bhalf * BHALF + bb;
        float sl0 = 0.f, sl1 = 0.f, sl2 = 0.f, sl3 = 0.f;
#pragma unroll
        for (int ii = 0; ii < IPW; ++ii) {
            const float* xp = x + ((size_t)b * IC + (size_t)(i0 + ii)) * 8;
            float u0 = 0.f, u1 = 0.f, u2 = 0.f, u3 = 0.f;
#pragma unroll
            for (int c = 0; c < 8; ++c) {
                const float xc = xp[c];
                u0 = fmaf(xc, w[ii][0  + c], u0);
                u1 = fmaf(xc, w[ii][8  + c], u1);
                u2 = fmaf(xc, w[ii][16 + c], u2);
                u3 = fmaf(xc, w[ii][24 + c], u3);
            }
            float cw;
            if (USEV == 0) {
                cw = 1.0f / 16.0f;
            } else {
                // agree = u . vprev  (vprev holds v1, or v1+v2 for the last pass)
                const float4 va = *(const float4*)(vprev + (((size_t)b * 16 + a) * 16 + dq * 4));
                float ag = u0 * va.x + u1 * va.y + u2 * va.z + u3 * va.w;
                ag += __shfl_xor(ag, 1);   // combine d-quads within the a-group
                ag += __shfl_xor(ag, 2);
                const float blog = 4096.0f * ag;
                // softmax over the 16 capsules (groups of 4 lanes); strides 4..32
                // don't touch lane bits 0-1, so replicated values sum exactly once per a.
                float m = blog;
                m = fmaxf(m, __shfl_xor(m, 4));
                m = fmaxf(m, __shfl_xor(m, 8));
                m = fmaxf(m, __shfl_xor(m, 16));
                m = fmaxf(m, __shfl_xor(m, 32));
                const float e = __expf(blog - m);
                float sum = e;
                sum += __shfl_xor(sum, 4);
                sum += __shfl_xor(sum, 8);
                sum += __shfl_xor(sum, 16);
                sum += __shfl_xor(sum, 32);
                cw = e / sum;
            }
            sl0 = fmaf(cw, u0, sl0);
            sl1 = fmaf(cw, u1, sl1);
            sl2 = fmaf(cw, u2, sl2);
            sl3 = fmaf(cw, u3, sl3);
        }
        // cross-wave reduce: lds[wave][a*16+d], then one atomic per (a,d).
        *(float4*)&lds[wu][lane * 4] = make_float4(sl0, sl1, sl2, sl3);
        __syncthreads();
        if (tid < 256) {
            float acc = 0.f;
#pragma unroll
            for (int wv = 0; wv < NWAVES; ++wv) acc += lds[wv][tid];
            unsafeAtomicAdd(&s_out[(size_t)b * 256 + tid], acc);
        }
        __syncthreads();
    }
}

// v = squash(s) [+ vprev];  optionally zero s afterwards for the next pass.
// One thread per (b, a) pair: 4096 threads.
template<int ADDP, int ZERO>
__global__ void caps_squash(float* __restrict__ s, float* __restrict__ vout,
                            const float* __restrict__ vprev)
{
    const int t = (int)blockIdx.x * 256 + (int)threadIdx.x;  // 0..4095
    float* sp = s + (size_t)t * 16;
    float4 f0 = *(float4*)(sp + 0);
    float4 f1 = *(float4*)(sp + 4);
    float4 f2 = *(float4*)(sp + 8);
    float4 f3 = *(float4*)(sp + 12);
    float sq = f0.x * f0.x + f0.y * f0.y + f0.z * f0.z + f0.w * f0.w
             + f1.x * f1.x + f1.y * f1.y + f1.z * f1.z + f1.w * f1.w
             + f2.x * f2.x + f2.y * f2.y + f2.z * f2.z + f2.w * f2.w
             + f3.x * f3.x + f3.y * f3.y + f3.z * f3.z + f3.w * f3.w;
    const float scale = sq / ((1.0f + sq) * sqrtf(sq + 1e-7f));
    float* vp = vout + (size_t)t * 16;
    float4 o0, o1, o2, o3;
    o0.x = f0.x * scale; o0.y = f0.y * scale; o0.z = f0.z * scale; o0.w = f0.w * scale;
    o1.x = f1.x * scale; o1.y = f1.y * scale; o1.z = f1.z * scale; o1.w = f1.w * scale;
    o2.x = f2.x * scale; o2.y = f2.y * scale; o2.z = f2.z * scale; o2.w = f2.w * scale;
    o3.x = f3.x * scale; o3.y = f3.y * scale; o3.z = f3.z * scale; o3.w = f3.w * scale;
    if (ADDP) {
        const float* pp = vprev + (size_t)t * 16;
        float4 p0 = *(const float4*)(pp + 0);
        float4 p1 = *(const float4*)(pp + 4);
        float4 p2 = *(const float4*)(pp + 8);
        float4 p3 = *(const float4*)(pp + 12);
        o0.x += p0.x; o0.y += p0.y; o0.z += p0.z; o0.w += p0.w;
        o1.x += p1.x; o1.y += p1.y; o1.z += p1.z; o1.w += p1.w;
        o2.x += p2.x; o2.y += p2.y; o2.z += p2.z; o2.w += p2.w;
        o3.x += p3.x; o3.y += p3.y; o3.z += p3.z; o3.w += p3.w;
    }
    *(float4*)(vp + 0)  = o0;
    *(float4*)(vp + 4)  = o1;
    *(float4*)(vp + 8)  = o2;
    *(float4*)(vp + 12) = o3;
    if (ZERO) {
        const float4 z = make_float4(0.f, 0.f, 0.f, 0.f);
        *(float4*)(sp + 0)  = z;
        *(float4*)(sp + 4)  = z;
        *(float4*)(sp + 8)  = z;
        *(float4*)(sp + 12) = z;
    }
}

__global__ void caps_zero(float* __restrict__ p)
{
    p[(size_t)blockIdx.x * 1024 + threadIdx.x] = 0.f;
}

extern "C" void kernel_launch(void* const* d_in, const int* in_sizes, int n_in,
                              void* d_out, int out_size, void* d_ws, size_t ws_size,
                              hipStream_t stream)
{
    const float* x = (const float*)d_in[0];   // [256, 4096, 8]
    const float* W = (const float*)d_in[1];   // [16, 4096, 16, 8]
    float* out = (float*)d_out;               // [256, 16, 16]
    float* s   = (float*)d_ws;                // 65536 floats: s accumulator
    float* v1  = s + 65536;                   // v1
    float* vs  = s + 2 * 65536;               // v1 + v2

    caps_zero<<<64, 1024, 0, stream>>>(s);
    // iter 1: uniform coupling c = 1/16
    caps_pass<0><<<256, 512, 0, stream>>>(x, W, nullptr, s);
    caps_squash<0, 1><<<16, 256, 0, stream>>>(s, v1, nullptr);      // v1 = squash(s); s = 0
    // iter 2: logits = IC * (u . v1)
    caps_pass<1><<<256, 512, 0, stream>>>(x, W, v1, s);
    caps_squash<1, 1><<<16, 256, 0, stream>>>(s, vs, v1);           // vs = squash(s) + v1; s = 0
    // iter 3: logits = IC * (u.v1 + u.v2) = IC * (u . vs)
    caps_pass<1><<<256, 512, 0, stream>>>(x, W, vs, s);
    caps_squash<0, 0><<<16, 256, 0, stream>>>(s, out, nullptr);     // out = squash(s)
}